// Round 11
// baseline (469.804 us; speedup 1.0000x reference)
//
#include <hip/hip_runtime.h>
#include <math.h>

#define NN 100000
#define NE 640000
#define MPAD2 100096  // NN rounded up to 128
#define NBLK 98       // ceil(NN / 1024)

typedef __bf16 bf16_t;
typedef bf16_t bf16x8 __attribute__((ext_vector_type(8)));
typedef float  f32x4  __attribute__((ext_vector_type(4)));

// ================= CSR build =================

__global__ __launch_bounds__(256) void k_hist(const int* __restrict__ dst,
                                              int* __restrict__ deg) {
    int e = blockIdx.x * 256 + threadIdx.x;
    if (e < NE) atomicAdd(&deg[dst[e]], 1);
}

__global__ __launch_bounds__(1024) void k_bsum(const int* __restrict__ deg,
                                               int* __restrict__ bsum) {
    __shared__ int warr[16];
    int t = threadIdx.x;
    int i = blockIdx.x * 1024 + t;
    int v = (i < NN) ? deg[i] : 0;
    int lane = t & 63, wid = t >> 6;
    #pragma unroll
    for (int off = 32; off > 0; off >>= 1) v += __shfl_xor(v, off, 64);
    if (lane == 0) warr[wid] = v;
    __syncthreads();
    if (t < 16) {
        int s = warr[t];
        #pragma unroll
        for (int off = 8; off > 0; off >>= 1) s += __shfl_xor(s, off, 64);
        if (t == 0) bsum[blockIdx.x] = s;
    }
}

__global__ __launch_bounds__(64) void k_bscan(const int* __restrict__ bsum,
        int* __restrict__ boff, int* __restrict__ rowptr) {
    int lane = threadIdx.x;
    int carry = 0;
    for (int base = 0; base < NBLK; base += 64) {
        int i = base + lane;
        int v = (i < NBLK) ? bsum[i] : 0;
        int s = v;
        #pragma unroll
        for (int off = 1; off < 64; off <<= 1) {
            int u = __shfl_up(s, off, 64);
            if (lane >= off) s += u;
        }
        if (i < NBLK) boff[i] = carry + s - v;
        carry += __shfl(s, 63, 64);
    }
    if (lane == 0) rowptr[NN] = NE;
}

__global__ __launch_bounds__(1024) void k_scan2(const int* __restrict__ deg,
        const int* __restrict__ boff, int* __restrict__ rowptr,
        int* __restrict__ cursor) {
    __shared__ int wsum[16];
    __shared__ int woff[16];
    int t = threadIdx.x;
    int lane = t & 63, wid = t >> 6;
    int i = blockIdx.x * 1024 + t;
    int v = (i < NN) ? deg[i] : 0;
    int s = v;
    #pragma unroll
    for (int off = 1; off < 64; off <<= 1) {
        int u = __shfl_up(s, off, 64);
        if (lane >= off) s += u;
    }
    if (lane == 63) wsum[wid] = s;
    __syncthreads();
    if (wid == 0) {
        int ws = (lane < 16) ? wsum[lane] : 0;
        #pragma unroll
        for (int off = 1; off < 16; off <<= 1) {
            int u = __shfl_up(ws, off, 64);
            if (lane >= off) ws += u;
        }
        if (lane < 16) woff[lane] = ws;
    }
    __syncthreads();
    if (i < NN) {
        int excl = boff[blockIdx.x] + (s - v) + (wid ? woff[wid - 1] : 0);
        rowptr[i] = excl;
        cursor[i] = excl;
    }
}

__global__ __launch_bounds__(256) void k_fill(const int* __restrict__ src,
        const int* __restrict__ dst, int* __restrict__ cursor,
        int* __restrict__ csr) {
    int e = blockIdx.x * 256 + threadIdx.x;
    if (e >= NE) return;
    int p = atomicAdd(&cursor[dst[e]], 1);
    csr[p] = src[e];
}

// ========== weight split (f32 -> hi/lo bf16) in MFMA B-fragment order ==========
// Wf[((ct*8 + it)*64 + lane)*8 + j] = W[col = ct*16 + (lane&15)]
//                                      [k   = it*32 + (lane>>4)*8 + j]
// -> wave loads are consecutive 16B/lane (1 KB coalesced), no LDS for W.

__global__ __launch_bounds__(256) void k_split_w1(const float* __restrict__ W1l,
        const float* __restrict__ W1r, bf16_t* __restrict__ Wfh,
        bf16_t* __restrict__ Wfl) {
    int j = blockIdx.x, t = threadIdx.x;   // j = col (0..255), t = k (0..255)
    float f = (t < 128) ? W1l[j * 128 + t] : W1r[j * 128 + (t - 128)];
    bf16_t h = (bf16_t)f;
    bf16_t l = (bf16_t)(f - (float)h);
    int ct = j >> 4, l16 = j & 15;
    int it = t >> 5, quad = (t & 31) >> 3, jj = t & 7;
    int idx = ((ct * 8 + it) * 64 + quad * 16 + l16) * 8 + jj;
    Wfh[idx] = h;
    Wfl[idx] = l;
}

__global__ __launch_bounds__(256) void k_split_w2(const float* __restrict__ W2l,
        const float* __restrict__ W2r, bf16_t* __restrict__ Wfh,
        bf16_t* __restrict__ Wfl) {
    int j = blockIdx.x, t = threadIdx.x;
    float f = (j < 128) ? W2l[j * 256 + t] : W2r[(j - 128) * 256 + t];
    bf16_t h = (bf16_t)f;
    bf16_t l = (bf16_t)(f - (float)h);
    int ct = j >> 4, l16 = j & 15;
    int it = t >> 5, quad = (t & 31) >> 3, jj = t & 7;
    int idx = ((ct * 8 + it) * 64 + quad * 16 + l16) * 8 + jj;
    Wfh[idx] = h;
    Wfl[idx] = l;
}

// ================= gather-mean for layer 1 (f32, 128 wide) =================

__global__ __launch_bounds__(256) void k_gather128s(const float* __restrict__ feat,
        const int* __restrict__ rowptr, const int* __restrict__ csr,
        float* __restrict__ agg) {
    int tid = blockIdx.x * 256 + threadIdx.x;
    int node = tid >> 5;
    if (node >= NN) return;
    int lane4 = (tid & 31) << 2;
    int beg = rowptr[node], end = rowptr[node + 1];
    float4 acc = make_float4(0.f, 0.f, 0.f, 0.f);
    int e = beg;
    for (; e + 1 < end; e += 2) {
        int s0 = csr[e], s1 = csr[e + 1];
        float4 v0 = *(const float4*)(feat + (size_t)s0 * 128 + lane4);
        float4 v1 = *(const float4*)(feat + (size_t)s1 * 128 + lane4);
        acc.x += v0.x + v1.x; acc.y += v0.y + v1.y;
        acc.z += v0.z + v1.z; acc.w += v0.w + v1.w;
    }
    if (e < end) {
        int s0 = csr[e];
        float4 v0 = *(const float4*)(feat + (size_t)s0 * 128 + lane4);
        acc.x += v0.x; acc.y += v0.y; acc.z += v0.z; acc.w += v0.w;
    }
    float iv = 1.0f / (float)max(end - beg, 1);
    acc.x *= iv; acc.y *= iv; acc.z *= iv; acc.w *= iv;
    *(float4*)(agg + (size_t)node * 128 + lane4) = acc;
}

// ============ split-bf16 MFMA GEMM, BM=128, W LDS-free, A double-buffered =======
// C = A @ W^T, 3-term split: C ~= Ah*Wh + Al*Wh + Ah*Wl.
// R10 post-mortem: neither MFMA (19%) nor LDS (~12%) nor HBM (31%) saturated ->
// the K-loop serialized on A-load (HBM ~900cyc) -> stage -> barrier each iter.
// Now: iter k issues k+1's A loads first, computes k from LDS buf p, then
// splits+stages into buf 1-p with ONE barrier/iter. Max wave skew = 1 barrier,
// and a wave only writes the buffer laggards aren't reading -> race-free.

#define PADK 2

__device__ __forceinline__ void splitv(float4 v0, float4 v1,
                                       bf16x8& h, bf16x8& l) {
    float f[8] = {v0.x, v0.y, v0.z, v0.w, v1.x, v1.y, v1.z, v1.w};
    #pragma unroll
    for (int i = 0; i < 8; i++) {
        bf16_t hi = (bf16_t)f[i];
        h[i] = hi;
        l[i] = (bf16_t)(f[i] - (float)hi);
    }
}

// Layer-1 GEMM, A = [agg | x] (each M x 128); fused epilogue h1 = relu(l2norm(C+b1))
__global__ __launch_bounds__(256, 2) void k_gemm_l1(const float* __restrict__ Aa,
        const float* __restrict__ Ax, const bf16_t* __restrict__ Wfh,
        const bf16_t* __restrict__ Wfl, const float* __restrict__ bias,
        float* __restrict__ H) {
    __shared__ bf16_t sAh[2][128][32 + PADK], sAl[2][128][32 + PADK];
    __shared__ float pr[128][4];
    int t = threadIdx.x;
    int wave = t >> 6, lane = t & 63, quad = lane >> 4, l16 = lane & 15;
    int r0 = blockIdx.x * 128;
    f32x4 acc[8][4] = {};
    int arow = t >> 1, ahalf = (t & 1) * 16;   // A staging: row, 16-f32 half
    int grow = r0 + arow; if (grow >= NN) grow = NN - 1;
    // stage iter 0 into buf 0
    {
        const float* p = &Aa[(size_t)grow * 128 + ahalf];
        bf16x8 h0, l0, h1, l1;
        splitv(*(const float4*)p, *(const float4*)(p + 4), h0, l0);
        splitv(*(const float4*)(p + 8), *(const float4*)(p + 12), h1, l1);
        *(bf16x8*)&sAh[0][arow][ahalf] = h0;
        *(bf16x8*)&sAh[0][arow][ahalf + 8] = h1;
        *(bf16x8*)&sAl[0][arow][ahalf] = l0;
        *(bf16x8*)&sAl[0][arow][ahalf + 8] = l1;
    }
    __syncthreads();
    int pb = 0;
    float4 na0, na1, na2, na3;
    for (int it = 0; it < 8; it++) {
        if (it < 7) {          // issue next iter's A loads; hide under MFMAs
            int k0n = (it + 1) * 32;
            const float* Asrc = (k0n < 128) ? Aa : Ax;
            int kb = (k0n < 128) ? k0n : (k0n - 128);
            const float* p = &Asrc[(size_t)grow * 128 + kb + ahalf];
            na0 = *(const float4*)p;        na1 = *(const float4*)(p + 4);
            na2 = *(const float4*)(p + 8);  na3 = *(const float4*)(p + 12);
        }
        // W fragment loads: coalesced global (L2-resident), no LDS
        bf16x8 bh[4], bl[4];
        #pragma unroll
        for (int nt = 0; nt < 4; nt++) {
            size_t fo = (size_t)(((wave * 4 + nt) * 8 + it) * 64 + lane) * 8;
            bh[nt] = *(const bf16x8*)&Wfh[fo];
            bl[nt] = *(const bf16x8*)&Wfl[fo];
        }
        #pragma unroll
        for (int mt = 0; mt < 8; mt++) {
            bf16x8 ah = *(bf16x8*)&sAh[pb][mt * 16 + l16][quad * 8];
            bf16x8 al = *(bf16x8*)&sAl[pb][mt * 16 + l16][quad * 8];
            #pragma unroll
            for (int nt = 0; nt < 4; nt++) {
                acc[mt][nt] = __builtin_amdgcn_mfma_f32_16x16x32_bf16(ah, bh[nt], acc[mt][nt], 0, 0, 0);
                acc[mt][nt] = __builtin_amdgcn_mfma_f32_16x16x32_bf16(al, bh[nt], acc[mt][nt], 0, 0, 0);
                acc[mt][nt] = __builtin_amdgcn_mfma_f32_16x16x32_bf16(ah, bl[nt], acc[mt][nt], 0, 0, 0);
            }
        }
        if (it < 7) {
            bf16x8 h0, l0, h1, l1;
            splitv(na0, na1, h0, l0);
            splitv(na2, na3, h1, l1);
            *(bf16x8*)&sAh[pb ^ 1][arow][ahalf] = h0;
            *(bf16x8*)&sAh[pb ^ 1][arow][ahalf + 8] = h1;
            *(bf16x8*)&sAl[pb ^ 1][arow][ahalf] = l0;
            *(bf16x8*)&sAl[pb ^ 1][arow][ahalf + 8] = l1;
            __syncthreads();
            pb ^= 1;
        }
    }
    // ---- fused epilogue: bias, row L2-norm across 256 cols, relu ----
    float bcol[4];
    #pragma unroll
    for (int nt = 0; nt < 4; nt++) bcol[nt] = bias[wave * 64 + nt * 16 + l16];
    #pragma unroll
    for (int mt = 0; mt < 8; mt++)
        #pragma unroll
        for (int nt = 0; nt < 4; nt++)
            #pragma unroll
            for (int rg = 0; rg < 4; rg++)
                acc[mt][nt][rg] += bcol[nt];
    float ss[8][4];
    #pragma unroll
    for (int mt = 0; mt < 8; mt++)
        #pragma unroll
        for (int rg = 0; rg < 4; rg++) {
            float s = 0.f;
            #pragma unroll
            for (int nt = 0; nt < 4; nt++) s += acc[mt][nt][rg] * acc[mt][nt][rg];
            #pragma unroll
            for (int off = 1; off < 16; off <<= 1) s += __shfl_xor(s, off, 64);
            ss[mt][rg] = s;
        }
    if (l16 == 0) {
        #pragma unroll
        for (int mt = 0; mt < 8; mt++)
            #pragma unroll
            for (int rg = 0; rg < 4; rg++)
                pr[mt * 16 + quad * 4 + rg][wave] = ss[mt][rg];
    }
    __syncthreads();
    #pragma unroll
    for (int mt = 0; mt < 8; mt++)
        #pragma unroll
        for (int rg = 0; rg < 4; rg++) {
            int lr = mt * 16 + quad * 4 + rg;
            int row = r0 + lr;
            if (row >= NN) continue;
            float tot = pr[lr][0] + pr[lr][1] + pr[lr][2] + pr[lr][3];
            float inv = 1.0f / fmaxf(sqrtf(tot), 1e-12f);
            #pragma unroll
            for (int nt = 0; nt < 4; nt++) {
                int col = wave * 64 + nt * 16 + l16;
                H[(size_t)row * 256 + col] = fmaxf(acc[mt][nt][rg] * inv, 0.f);
            }
        }
}

// Layer-2 GEMM: C2 = h1 @ [W2l;W2r]^T, plain f32 store, BM=128, A double-buffered
__global__ __launch_bounds__(256, 2) void k_gemm_l2(const float* __restrict__ A,
        const bf16_t* __restrict__ Wfh, const bf16_t* __restrict__ Wfl,
        float* __restrict__ C) {
    __shared__ bf16_t sAh[2][128][32 + PADK], sAl[2][128][32 + PADK];
    int t = threadIdx.x;
    int wave = t >> 6, lane = t & 63, quad = lane >> 4, l16 = lane & 15;
    int r0 = blockIdx.x * 128;
    f32x4 acc[8][4] = {};
    int arow = t >> 1, ahalf = (t & 1) * 16;
    int grow = r0 + arow; if (grow >= NN) grow = NN - 1;
    {
        const float* p = &A[(size_t)grow * 256 + ahalf];
        bf16x8 h0, l0, h1, l1;
        splitv(*(const float4*)p, *(const float4*)(p + 4), h0, l0);
        splitv(*(const float4*)(p + 8), *(const float4*)(p + 12), h1, l1);
        *(bf16x8*)&sAh[0][arow][ahalf] = h0;
        *(bf16x8*)&sAh[0][arow][ahalf + 8] = h1;
        *(bf16x8*)&sAl[0][arow][ahalf] = l0;
        *(bf16x8*)&sAl[0][arow][ahalf + 8] = l1;
    }
    __syncthreads();
    int pb = 0;
    float4 na0, na1, na2, na3;
    for (int it = 0; it < 8; it++) {
        if (it < 7) {
            int k0n = (it + 1) * 32;
            const float* p = &A[(size_t)grow * 256 + k0n + ahalf];
            na0 = *(const float4*)p;        na1 = *(const float4*)(p + 4);
            na2 = *(const float4*)(p + 8);  na3 = *(const float4*)(p + 12);
        }
        bf16x8 bh[4], bl[4];
        #pragma unroll
        for (int nt = 0; nt < 4; nt++) {
            size_t fo = (size_t)(((wave * 4 + nt) * 8 + it) * 64 + lane) * 8;
            bh[nt] = *(const bf16x8*)&Wfh[fo];
            bl[nt] = *(const bf16x8*)&Wfl[fo];
        }
        #pragma unroll
        for (int mt = 0; mt < 8; mt++) {
            bf16x8 ah = *(bf16x8*)&sAh[pb][mt * 16 + l16][quad * 8];
            bf16x8 al = *(bf16x8*)&sAl[pb][mt * 16 + l16][quad * 8];
            #pragma unroll
            for (int nt = 0; nt < 4; nt++) {
                acc[mt][nt] = __builtin_amdgcn_mfma_f32_16x16x32_bf16(ah, bh[nt], acc[mt][nt], 0, 0, 0);
                acc[mt][nt] = __builtin_amdgcn_mfma_f32_16x16x32_bf16(al, bh[nt], acc[mt][nt], 0, 0, 0);
                acc[mt][nt] = __builtin_amdgcn_mfma_f32_16x16x32_bf16(ah, bl[nt], acc[mt][nt], 0, 0, 0);
            }
        }
        if (it < 7) {
            bf16x8 h0, l0, h1, l1;
            splitv(na0, na1, h0, l0);
            splitv(na2, na3, h1, l1);
            *(bf16x8*)&sAh[pb ^ 1][arow][ahalf] = h0;
            *(bf16x8*)&sAh[pb ^ 1][arow][ahalf + 8] = h1;
            *(bf16x8*)&sAl[pb ^ 1][arow][ahalf] = l0;
            *(bf16x8*)&sAl[pb ^ 1][arow][ahalf + 8] = l1;
            __syncthreads();
            pb ^= 1;
        }
    }
    #pragma unroll
    for (int mt = 0; mt < 8; mt++)
        #pragma unroll
        for (int rg = 0; rg < 4; rg++) {
            int row = r0 + mt * 16 + quad * 4 + rg;
            if (row >= NN) continue;
            #pragma unroll
            for (int nt = 0; nt < 4; nt++) {
                int col = wave * 64 + nt * 16 + l16;
                C[(size_t)row * 256 + col] = acc[mt][nt][rg];
            }
        }
}

// ==== fused layer-2 tail: gather-mean p2 + combine + norm + q3 ====

__global__ __launch_bounds__(256) void k_gather_combine(const float* __restrict__ C2,
        const int* __restrict__ rowptr, const int* __restrict__ csr,
        const float* __restrict__ b2, const float* __restrict__ W3l,
        float* __restrict__ h2, float* __restrict__ q3) {
    __shared__ float sw[256];
    int t = threadIdx.x;
    sw[t] = W3l[t];
    __syncthreads();
    int tid = blockIdx.x * 256 + t;
    int node = tid >> 5;
    if (node >= NN) return;
    int l = tid & 31;
    int lane4 = l << 2;
    int beg = rowptr[node], end = rowptr[node + 1];
    float4 acc = make_float4(0.f, 0.f, 0.f, 0.f);
    int e = beg;
    for (; e + 1 < end; e += 2) {
        int s0 = csr[e], s1 = csr[e + 1];
        float4 v0 = *(const float4*)(C2 + (size_t)s0 * 256 + lane4);
        float4 v1 = *(const float4*)(C2 + (size_t)s1 * 256 + lane4);
        acc.x += v0.x + v1.x; acc.y += v0.y + v1.y;
        acc.z += v0.z + v1.z; acc.w += v0.w + v1.w;
    }
    if (e < end) {
        int s0 = csr[e];
        float4 v0 = *(const float4*)(C2 + (size_t)s0 * 256 + lane4);
        acc.x += v0.x; acc.y += v0.y; acc.z += v0.z; acc.w += v0.w;
    }
    float iv = 1.0f / (float)max(end - beg, 1);
    float4 r = *(const float4*)&C2[(size_t)node * 256 + 128 + lane4];
    float4 b = *(const float4*)&b2[lane4];
    float v0 = acc.x * iv + r.x + b.x;
    float v1 = acc.y * iv + r.y + b.y;
    float v2 = acc.z * iv + r.z + b.z;
    float v3 = acc.w * iv + r.w + b.w;
    float s = v0 * v0 + v1 * v1 + v2 * v2 + v3 * v3;
    #pragma unroll
    for (int off = 16; off > 0; off >>= 1) s += __shfl_xor(s, off, 64);
    float invn = 1.0f / fmaxf(sqrtf(s), 1e-12f);
    float4 o;
    o.x = fmaxf(v0 * invn, 0.f); o.y = fmaxf(v1 * invn, 0.f);
    o.z = fmaxf(v2 * invn, 0.f); o.w = fmaxf(v3 * invn, 0.f);
    *(float4*)&h2[(size_t)node * 128 + lane4] = o;
    float a0 = o.x * sw[lane4] + o.y * sw[lane4+1] + o.z * sw[lane4+2] + o.w * sw[lane4+3];
    float a1 = o.x * sw[128+lane4] + o.y * sw[129+lane4] + o.z * sw[130+lane4] + o.w * sw[131+lane4];
    #pragma unroll
    for (int off = 16; off > 0; off >>= 1) {
        a0 += __shfl_xor(a0, off, 64);
        a1 += __shfl_xor(a1, off, 64);
    }
    if (l == 0) {
        q3[2 * node] = a0;
        q3[2 * node + 1] = a1;
    }
}

// ================= final (absorbs the 2-wide q3 gather) =================

__global__ __launch_bounds__(256) void k_final(const float* __restrict__ h2,
        const float* __restrict__ W3r, const float* __restrict__ b3,
        const float* __restrict__ q3, const int* __restrict__ rowptr,
        const int* __restrict__ csr, float* __restrict__ out) {
    __shared__ float sw[256];
    int t = threadIdx.x;
    sw[t] = W3r[t];
    __syncthreads();
    int i = blockIdx.x * 256 + t;
    if (i >= NN) return;
    int beg = rowptr[i], end = rowptr[i + 1];
    float g0 = 0.f, g1 = 0.f;
    for (int e = beg; e < end; e++) {
        int s = csr[e];
        g0 += q3[2 * s];
        g1 += q3[2 * s + 1];
    }
    float ivd = 1.0f / (float)max(end - beg, 1);
    g0 *= ivd; g1 *= ivd;
    const float4* row = (const float4*)(h2 + (size_t)i * 128);
    float a0 = 0.f, a1 = 0.f;
    #pragma unroll
    for (int q = 0; q < 32; q++) {
        float4 v = row[q];
        a0 += v.x * sw[4*q] + v.y * sw[4*q+1] + v.z * sw[4*q+2] + v.w * sw[4*q+3];
        a1 += v.x * sw[128+4*q] + v.y * sw[129+4*q] + v.z * sw[130+4*q] + v.w * sw[131+4*q];
    }
    float v0 = g0 + a0 + b3[0];
    float v1 = g1 + a1 + b3[1];
    float invn = 1.0f / fmaxf(sqrtf(v0 * v0 + v1 * v1), 1e-12f);
    v0 *= invn; v1 *= invn;
    float mx = fmaxf(v0, v1);
    float l = logf(expf(v0 - mx) + expf(v1 - mx));
    out[2 * i] = v0 - mx - l;
    out[2 * i + 1] = v1 - mx - l;
}

// ================= launch =================

extern "C" void kernel_launch(void* const* d_in, const int* in_sizes, int n_in,
                              void* d_out, int out_size, void* d_ws, size_t ws_size,
                              hipStream_t stream) {
    const float* x   = (const float*)d_in[0];
    const int*   ei  = (const int*)d_in[1];
    const float* W1l = (const float*)d_in[2];
    const float* W1r = (const float*)d_in[3];
    const float* b1  = (const float*)d_in[4];
    const float* W2l = (const float*)d_in[5];
    const float* W2r = (const float*)d_in[6];
    const float* b2  = (const float*)d_in[7];
    const float* W3l = (const float*)d_in[8];
    const float* W3r = (const float*)d_in[9];
    const float* b3  = (const float*)d_in[10];
    float* out = (float*)d_out;
    const int* src = ei;
    const int* dst = ei + NE;

    // ---- workspace layout ----
    int* deg    = (int*)d_ws;                     // 102400
    int* rowptr = deg + 102400;
    int* cursor = rowptr + 102400;
    int* csr    = cursor + 102400;                // 655360
    int* bsum   = csr + 655360;                   // 128
    int* boff   = bsum + 128;                     // 128
    bf16_t* W1h  = (bf16_t*)(boff + 128);         // 65536 bf16 each (frag order)
    bf16_t* W1lo = W1h + 65536;
    bf16_t* W2h  = W1lo + 65536;
    bf16_t* W2lo = W2h + 65536;
    float* aggA = (float*)(W2lo + 65536);         // 12.8M f32 (layer-1 agg)
    float* h1   = aggA + 12800000;                // NN*256 f32 (reused as h2)
    float* C2   = h1 + (size_t)MPAD2 * 256;       // NN*256 f32
    float* q3   = C2 + (size_t)MPAD2 * 256;       // 200000
    float* h2   = h1;                             // reuse after L2 GEMM consumed h1

    // ---- CSR build (multi-block scan) ----
    hipMemsetAsync(deg, 0, NN * sizeof(int), stream);
    k_hist<<<(NE + 255) / 256, 256, 0, stream>>>(dst, deg);
    k_bsum<<<NBLK, 1024, 0, stream>>>(deg, bsum);
    k_bscan<<<1, 64, 0, stream>>>(bsum, boff, rowptr);
    k_scan2<<<NBLK, 1024, 0, stream>>>(deg, boff, rowptr, cursor);
    k_fill<<<(NE + 255) / 256, 256, 0, stream>>>(src, dst, cursor, csr);

    // ---- weight split (fragment order) ----
    k_split_w1<<<256, 256, 0, stream>>>(W1l, W1r, W1h, W1lo);
    k_split_w2<<<256, 256, 0, stream>>>(W2l, W2r, W2h, W2lo);

    // ---- layer 1 ----
    k_gather128s<<<(NN * 32 + 255) / 256, 256, 0, stream>>>(x, rowptr, csr, aggA);
    k_gemm_l1<<<MPAD2 / 128, 256, 0, stream>>>(aggA, x, W1h, W1lo, b1, h1);

    // ---- layer 2 (gather+combine+q3 fused) ----
    k_gemm_l2<<<MPAD2 / 128, 256, 0, stream>>>(h1, W2h, W2lo, C2);
    k_gather_combine<<<(NN * 32 + 255) / 256, 256, 0, stream>>>(C2, rowptr, csr, b2, W3l, h2, q3);

    // ---- layer 3 ----
    k_final<<<(NN + 255) / 256, 256, 0, stream>>>(h2, W3r, b3, q3, rowptr, csr, out);
}

// Round 12
// 399.751 us; speedup vs baseline: 1.1752x; 1.1752x over previous
//
#include <hip/hip_runtime.h>
#include <math.h>

#define NN 100000
#define NE 640000
#define NBLK 98       // ceil(NN / 1024)
#define GBLK 1563     // ceil(NN / 64)

typedef __bf16 bf16_t;
typedef bf16_t bf16x8 __attribute__((ext_vector_type(8)));
typedef float  f32x4  __attribute__((ext_vector_type(4)));

// ================= CSR build =================

__global__ __launch_bounds__(256) void k_hist(const int* __restrict__ dst,
                                              int* __restrict__ deg) {
    int e = blockIdx.x * 256 + threadIdx.x;
    if (e < NE) atomicAdd(&deg[dst[e]], 1);
}

__global__ __launch_bounds__(1024) void k_bsum(const int* __restrict__ deg,
                                               int* __restrict__ bsum) {
    __shared__ int warr[16];
    int t = threadIdx.x;
    int i = blockIdx.x * 1024 + t;
    int v = (i < NN) ? deg[i] : 0;
    int lane = t & 63, wid = t >> 6;
    #pragma unroll
    for (int off = 32; off > 0; off >>= 1) v += __shfl_xor(v, off, 64);
    if (lane == 0) warr[wid] = v;
    __syncthreads();
    if (t < 16) {
        int s = warr[t];
        #pragma unroll
        for (int off = 8; off > 0; off >>= 1) s += __shfl_xor(s, off, 64);
        if (t == 0) bsum[blockIdx.x] = s;
    }
}

__global__ __launch_bounds__(64) void k_bscan(const int* __restrict__ bsum,
        int* __restrict__ boff, int* __restrict__ rowptr) {
    int lane = threadIdx.x;
    int carry = 0;
    for (int base = 0; base < NBLK; base += 64) {
        int i = base + lane;
        int v = (i < NBLK) ? bsum[i] : 0;
        int s = v;
        #pragma unroll
        for (int off = 1; off < 64; off <<= 1) {
            int u = __shfl_up(s, off, 64);
            if (lane >= off) s += u;
        }
        if (i < NBLK) boff[i] = carry + s - v;
        carry += __shfl(s, 63, 64);
    }
    if (lane == 0) rowptr[NN] = NE;
}

__global__ __launch_bounds__(1024) void k_scan2(const int* __restrict__ deg,
        const int* __restrict__ boff, int* __restrict__ rowptr,
        int* __restrict__ cursor) {
    __shared__ int wsum[16];
    __shared__ int woff[16];
    int t = threadIdx.x;
    int lane = t & 63, wid = t >> 6;
    int i = blockIdx.x * 1024 + t;
    int v = (i < NN) ? deg[i] : 0;
    int s = v;
    #pragma unroll
    for (int off = 1; off < 64; off <<= 1) {
        int u = __shfl_up(s, off, 64);
        if (lane >= off) s += u;
    }
    if (lane == 63) wsum[wid] = s;
    __syncthreads();
    if (wid == 0) {
        int ws = (lane < 16) ? wsum[lane] : 0;
        #pragma unroll
        for (int off = 1; off < 16; off <<= 1) {
            int u = __shfl_up(ws, off, 64);
            if (lane >= off) ws += u;
        }
        if (lane < 16) woff[lane] = ws;
    }
    __syncthreads();
    if (i < NN) {
        int excl = boff[blockIdx.x] + (s - v) + (wid ? woff[wid - 1] : 0);
        rowptr[i] = excl;
        cursor[i] = excl;
    }
}

__global__ __launch_bounds__(256) void k_fill(const int* __restrict__ src,
        const int* __restrict__ dst, int* __restrict__ cursor,
        int* __restrict__ csr) {
    int e = blockIdx.x * 256 + threadIdx.x;
    if (e >= NE) return;
    int p = atomicAdd(&cursor[dst[e]], 1);
    csr[p] = src[e];
}

// ========== weight split (f32 -> hi/lo bf16) in MFMA B-fragment order ==========
// Wf[((ct*8 + it)*64 + lane)*8 + j] = W[col = ct*16 + (lane&15)]
//                                      [k   = it*32 + (lane>>4)*8 + j]
// Both W1cat and W2cat in ONE kernel (512 blocks).

__global__ __launch_bounds__(256) void k_split_w(const float* __restrict__ W1l,
        const float* __restrict__ W1r, const float* __restrict__ W2l,
        const float* __restrict__ W2r, bf16_t* __restrict__ W1fh,
        bf16_t* __restrict__ W1fl, bf16_t* __restrict__ W2fh,
        bf16_t* __restrict__ W2fl) {
    int b = blockIdx.x, t = threadIdx.x;
    float f;
    bf16_t* Wfh;
    bf16_t* Wfl;
    int j;
    if (b < 256) {        // W1cat[j] = [W1l[j,:] | W1r[j,:]]
        j = b;
        f = (t < 128) ? W1l[j * 128 + t] : W1r[j * 128 + (t - 128)];
        Wfh = W1fh; Wfl = W1fl;
    } else {              // W2cat rows 0..127 = W2l, 128..255 = W2r
        j = b - 256;
        f = (j < 128) ? W2l[j * 256 + t] : W2r[(j - 128) * 256 + t];
        Wfh = W2fh; Wfl = W2fl;
    }
    bf16_t h = (bf16_t)f;
    bf16_t l = (bf16_t)(f - (float)h);
    int idx = (((j >> 4) * 8 + (t >> 5)) * 64 + ((t >> 3) & 3) * 16 + (j & 15)) * 8 + (t & 7);
    Wfh[idx] = h;
    Wfl[idx] = l;
}

// ================= gather-mean for layer 1 (f32, 128 wide) =================

__global__ __launch_bounds__(256) void k_gather128s(const float* __restrict__ feat,
        const int* __restrict__ rowptr, const int* __restrict__ csr,
        float* __restrict__ agg) {
    int tid = blockIdx.x * 256 + threadIdx.x;
    int node = tid >> 5;
    if (node >= NN) return;
    int lane4 = (tid & 31) << 2;
    int beg = rowptr[node], end = rowptr[node + 1];
    float4 acc = make_float4(0.f, 0.f, 0.f, 0.f);
    int e = beg;
    for (; e + 1 < end; e += 2) {
        int s0 = csr[e], s1 = csr[e + 1];
        float4 v0 = *(const float4*)(feat + (size_t)s0 * 128 + lane4);
        float4 v1 = *(const float4*)(feat + (size_t)s1 * 128 + lane4);
        acc.x += v0.x + v1.x; acc.y += v0.y + v1.y;
        acc.z += v0.z + v1.z; acc.w += v0.w + v1.w;
    }
    if (e < end) {
        int s0 = csr[e];
        float4 v0 = *(const float4*)(feat + (size_t)s0 * 128 + lane4);
        acc.x += v0.x; acc.y += v0.y; acc.z += v0.z; acc.w += v0.w;
    }
    float iv = 1.0f / (float)max(end - beg, 1);
    acc.x *= iv; acc.y *= iv; acc.z *= iv; acc.w *= iv;
    *(float4*)(agg + (size_t)node * 128 + lane4) = acc;
}

// ============ FUSED layer-1 + layer-2 GEMM =============
// Phase 1: h1_tile = relu(l2norm([agg|x] @ W1cat^T + b1))   (K-loop 1, R10 form)
// h1_tile (64 x 256) goes to LDS in MFMA A-FRAGMENT ORDER (hi/lo split) --
// never touches global (saves the 204 MB h1 roundtrip of the split kernels).
// Phase 2: C2_tile = h1_tile @ W2cat^T                       (K-loop 2:
// A-frags straight from read-only LDS, W2-frags from global frag-order;
// ZERO staging, ZERO barriers in loop 2).
// Frag-order index for element [r][c] (r=row 0..63, c=k 0..255):
//   idx = (((r>>4)*8 + (c>>5))*64 + ((c>>3)&3)*16 + (r&15))*8 + (c&7)
// -> reader lane (quad*16+l16) of frag (mt,it) reads 16 contiguous bytes:
//    baseline conflict-free ds_read_b128.

__device__ __forceinline__ void splitv(float4 v0, float4 v1,
                                       bf16x8& h, bf16x8& l) {
    float f[8] = {v0.x, v0.y, v0.z, v0.w, v1.x, v1.y, v1.z, v1.w};
    #pragma unroll
    for (int i = 0; i < 8; i++) {
        bf16_t hi = (bf16_t)f[i];
        h[i] = hi;
        l[i] = (bf16_t)(f[i] - (float)hi);
    }
}

__global__ __launch_bounds__(256, 2) void k_gemm_fused(const float* __restrict__ Aa,
        const float* __restrict__ Ax, const bf16_t* __restrict__ W1fh,
        const bf16_t* __restrict__ W1fl, const bf16_t* __restrict__ W2fh,
        const bf16_t* __restrict__ W2fl, const float* __restrict__ bias,
        float* __restrict__ C2) {
    __shared__ bf16_t sAh[64][34], sAl[64][34];      // phase-1 A staging (17-dw stride)
    __shared__ bf16_t sHf[64 * 256], sLf[64 * 256];  // h1 tile, fragment order
    __shared__ float pr[64][4];
    int t = threadIdx.x;
    int wave = t >> 6, lane = t & 63, quad = lane >> 4, l16 = lane & 15;
    int r0 = blockIdx.x * 64;
    f32x4 acc[4][4] = {};
    int arow = t >> 2, aseg = t & 3;                 // staging: 8 f32 per thread
    int grow = r0 + arow; if (grow >= NN) grow = NN - 1;
    // ---------- phase 1 K-loop (R10-proven shape) ----------
    for (int it = 0; it < 8; it++) {
        int k0 = it * 32;
        bf16x8 bh[4], bl[4];
        #pragma unroll
        for (int nt = 0; nt < 4; nt++) {
            size_t fo = (size_t)(((wave * 4 + nt) * 8 + it) * 64 + lane) * 8;
            bh[nt] = *(const bf16x8*)&W1fh[fo];
            bl[nt] = *(const bf16x8*)&W1fl[fo];
        }
        const float* Asrc = (k0 < 128) ? Aa : Ax;
        int kb = (k0 < 128) ? k0 : (k0 - 128);
        __syncthreads();
        {
            const float* p = &Asrc[(size_t)grow * 128 + kb + aseg * 8];
            bf16x8 h8, l8;
            splitv(*(const float4*)p, *(const float4*)(p + 4), h8, l8);
            *(bf16x8*)&sAh[arow][aseg * 8] = h8;
            *(bf16x8*)&sAl[arow][aseg * 8] = l8;
        }
        __syncthreads();
        #pragma unroll
        for (int mt = 0; mt < 4; mt++) {
            bf16x8 ah = *(bf16x8*)&sAh[mt * 16 + l16][quad * 8];
            bf16x8 al = *(bf16x8*)&sAl[mt * 16 + l16][quad * 8];
            #pragma unroll
            for (int nt = 0; nt < 4; nt++) {
                acc[mt][nt] = __builtin_amdgcn_mfma_f32_16x16x32_bf16(ah, bh[nt], acc[mt][nt], 0, 0, 0);
                acc[mt][nt] = __builtin_amdgcn_mfma_f32_16x16x32_bf16(al, bh[nt], acc[mt][nt], 0, 0, 0);
                acc[mt][nt] = __builtin_amdgcn_mfma_f32_16x16x32_bf16(ah, bl[nt], acc[mt][nt], 0, 0, 0);
            }
        }
    }
    // ---------- epilogue 1: bias + row L2-norm + relu ----------
    float bcol[4];
    #pragma unroll
    for (int nt = 0; nt < 4; nt++) bcol[nt] = bias[wave * 64 + nt * 16 + l16];
    #pragma unroll
    for (int mt = 0; mt < 4; mt++)
        #pragma unroll
        for (int nt = 0; nt < 4; nt++)
            #pragma unroll
            for (int rg = 0; rg < 4; rg++)
                acc[mt][nt][rg] += bcol[nt];
    float ss[4][4];
    #pragma unroll
    for (int mt = 0; mt < 4; mt++)
        #pragma unroll
        for (int rg = 0; rg < 4; rg++) {
            float s = 0.f;
            #pragma unroll
            for (int nt = 0; nt < 4; nt++) s += acc[mt][nt][rg] * acc[mt][nt][rg];
            #pragma unroll
            for (int off = 1; off < 16; off <<= 1) s += __shfl_xor(s, off, 64);
            ss[mt][rg] = s;
        }
    if (l16 == 0) {
        #pragma unroll
        for (int mt = 0; mt < 4; mt++)
            #pragma unroll
            for (int rg = 0; rg < 4; rg++)
                pr[mt * 16 + quad * 4 + rg][wave] = ss[mt][rg];
    }
    __syncthreads();
    // ---------- h1 tile -> LDS (fragment order, hi/lo) ----------
    #pragma unroll
    for (int mt = 0; mt < 4; mt++)
        #pragma unroll
        for (int rg = 0; rg < 4; rg++) {
            int r = mt * 16 + quad * 4 + rg;
            float tot = pr[r][0] + pr[r][1] + pr[r][2] + pr[r][3];
            float inv = 1.0f / fmaxf(sqrtf(tot), 1e-12f);
            #pragma unroll
            for (int nt = 0; nt < 4; nt++) {
                int c = wave * 64 + nt * 16 + l16;
                float v = fmaxf(acc[mt][nt][rg] * inv, 0.f);
                bf16_t h = (bf16_t)v;
                bf16_t l = (bf16_t)(v - (float)h);
                int idx = (((r >> 4) * 8 + (c >> 5)) * 64 + ((c >> 3) & 3) * 16 + (r & 15)) * 8 + (c & 7);
                sHf[idx] = h;
                sLf[idx] = l;
            }
        }
    __syncthreads();
    // ---------- phase 2 K-loop: no staging, no barriers ----------
    f32x4 acc2[4][4] = {};
    for (int it = 0; it < 8; it++) {
        bf16x8 bh[4], bl[4];
        #pragma unroll
        for (int nt = 0; nt < 4; nt++) {
            size_t fo = (size_t)(((wave * 4 + nt) * 8 + it) * 64 + lane) * 8;
            bh[nt] = *(const bf16x8*)&W2fh[fo];
            bl[nt] = *(const bf16x8*)&W2fl[fo];
        }
        #pragma unroll
        for (int mt = 0; mt < 4; mt++) {
            int fb = ((mt * 8 + it) * 64 + lane) * 8;
            bf16x8 ah = *(bf16x8*)&sHf[fb];
            bf16x8 al = *(bf16x8*)&sLf[fb];
            #pragma unroll
            for (int nt = 0; nt < 4; nt++) {
                acc2[mt][nt] = __builtin_amdgcn_mfma_f32_16x16x32_bf16(ah, bh[nt], acc2[mt][nt], 0, 0, 0);
                acc2[mt][nt] = __builtin_amdgcn_mfma_f32_16x16x32_bf16(al, bh[nt], acc2[mt][nt], 0, 0, 0);
                acc2[mt][nt] = __builtin_amdgcn_mfma_f32_16x16x32_bf16(ah, bl[nt], acc2[mt][nt], 0, 0, 0);
            }
        }
    }
    #pragma unroll
    for (int mt = 0; mt < 4; mt++)
        #pragma unroll
        for (int rg = 0; rg < 4; rg++) {
            int row = r0 + mt * 16 + quad * 4 + rg;
            if (row >= NN) continue;
            #pragma unroll
            for (int nt = 0; nt < 4; nt++) {
                int col = wave * 64 + nt * 16 + l16;
                C2[(size_t)row * 256 + col] = acc2[mt][nt][rg];
            }
        }
}

// ==== fused layer-2 tail: gather-mean p2 + combine + norm + q3 ====

__global__ __launch_bounds__(256) void k_gather_combine(const float* __restrict__ C2,
        const int* __restrict__ rowptr, const int* __restrict__ csr,
        const float* __restrict__ b2, const float* __restrict__ W3l,
        float* __restrict__ h2, float* __restrict__ q3) {
    __shared__ float sw[256];
    int t = threadIdx.x;
    sw[t] = W3l[t];
    __syncthreads();
    int tid = blockIdx.x * 256 + t;
    int node = tid >> 5;
    if (node >= NN) return;
    int l = tid & 31;
    int lane4 = l << 2;
    int beg = rowptr[node], end = rowptr[node + 1];
    float4 acc = make_float4(0.f, 0.f, 0.f, 0.f);
    int e = beg;
    for (; e + 1 < end; e += 2) {
        int s0 = csr[e], s1 = csr[e + 1];
        float4 v0 = *(const float4*)(C2 + (size_t)s0 * 256 + lane4);
        float4 v1 = *(const float4*)(C2 + (size_t)s1 * 256 + lane4);
        acc.x += v0.x + v1.x; acc.y += v0.y + v1.y;
        acc.z += v0.z + v1.z; acc.w += v0.w + v1.w;
    }
    if (e < end) {
        int s0 = csr[e];
        float4 v0 = *(const float4*)(C2 + (size_t)s0 * 256 + lane4);
        acc.x += v0.x; acc.y += v0.y; acc.z += v0.z; acc.w += v0.w;
    }
    float iv = 1.0f / (float)max(end - beg, 1);
    float4 r = *(const float4*)&C2[(size_t)node * 256 + 128 + lane4];
    float4 b = *(const float4*)&b2[lane4];
    float v0 = acc.x * iv + r.x + b.x;
    float v1 = acc.y * iv + r.y + b.y;
    float v2 = acc.z * iv + r.z + b.z;
    float v3 = acc.w * iv + r.w + b.w;
    float s = v0 * v0 + v1 * v1 + v2 * v2 + v3 * v3;
    #pragma unroll
    for (int off = 16; off > 0; off >>= 1) s += __shfl_xor(s, off, 64);
    float invn = 1.0f / fmaxf(sqrtf(s), 1e-12f);
    float4 o;
    o.x = fmaxf(v0 * invn, 0.f); o.y = fmaxf(v1 * invn, 0.f);
    o.z = fmaxf(v2 * invn, 0.f); o.w = fmaxf(v3 * invn, 0.f);
    *(float4*)&h2[(size_t)node * 128 + lane4] = o;
    float a0 = o.x * sw[lane4] + o.y * sw[lane4+1] + o.z * sw[lane4+2] + o.w * sw[lane4+3];
    float a1 = o.x * sw[128+lane4] + o.y * sw[129+lane4] + o.z * sw[130+lane4] + o.w * sw[131+lane4];
    #pragma unroll
    for (int off = 16; off > 0; off >>= 1) {
        a0 += __shfl_xor(a0, off, 64);
        a1 += __shfl_xor(a1, off, 64);
    }
    if (l == 0) {
        q3[2 * node] = a0;
        q3[2 * node + 1] = a1;
    }
}

// ================= final (absorbs the 2-wide q3 gather) =================

__global__ __launch_bounds__(256) void k_final(const float* __restrict__ h2,
        const float* __restrict__ W3r, const float* __restrict__ b3,
        const float* __restrict__ q3, const int* __restrict__ rowptr,
        const int* __restrict__ csr, float* __restrict__ out) {
    __shared__ float sw[256];
    int t = threadIdx.x;
    sw[t] = W3r[t];
    __syncthreads();
    int i = blockIdx.x * 256 + t;
    if (i >= NN) return;
    int beg = rowptr[i], end = rowptr[i + 1];
    float g0 = 0.f, g1 = 0.f;
    for (int e = beg; e < end; e++) {
        int s = csr[e];
        g0 += q3[2 * s];
        g1 += q3[2 * s + 1];
    }
    float ivd = 1.0f / (float)max(end - beg, 1);
    g0 *= ivd; g1 *= ivd;
    const float4* row = (const float4*)(h2 + (size_t)i * 128);
    float a0 = 0.f, a1 = 0.f;
    #pragma unroll
    for (int q = 0; q < 32; q++) {
        float4 v = row[q];
        a0 += v.x * sw[4*q] + v.y * sw[4*q+1] + v.z * sw[4*q+2] + v.w * sw[4*q+3];
        a1 += v.x * sw[128+4*q] + v.y * sw[129+4*q] + v.z * sw[130+4*q] + v.w * sw[131+4*q];
    }
    float v0 = g0 + a0 + b3[0];
    float v1 = g1 + a1 + b3[1];
    float invn = 1.0f / fmaxf(sqrtf(v0 * v0 + v1 * v1), 1e-12f);
    v0 *= invn; v1 *= invn;
    float mx = fmaxf(v0, v1);
    float l = logf(expf(v0 - mx) + expf(v1 - mx));
    out[2 * i] = v0 - mx - l;
    out[2 * i + 1] = v1 - mx - l;
}

// ================= launch =================

extern "C" void kernel_launch(void* const* d_in, const int* in_sizes, int n_in,
                              void* d_out, int out_size, void* d_ws, size_t ws_size,
                              hipStream_t stream) {
    const float* x   = (const float*)d_in[0];
    const int*   ei  = (const int*)d_in[1];
    const float* W1l = (const float*)d_in[2];
    const float* W1r = (const float*)d_in[3];
    const float* b1  = (const float*)d_in[4];
    const float* W2l = (const float*)d_in[5];
    const float* W2r = (const float*)d_in[6];
    const float* b2  = (const float*)d_in[7];
    const float* W3l = (const float*)d_in[8];
    const float* W3r = (const float*)d_in[9];
    const float* b3  = (const float*)d_in[10];
    float* out = (float*)d_out;
    const int* src = ei;
    const int* dst = ei + NE;

    // ---- workspace layout ----
    int* deg    = (int*)d_ws;                     // 102400
    int* rowptr = deg + 102400;
    int* cursor = rowptr + 102400;
    int* csr    = cursor + 102400;                // 655360
    int* bsum   = csr + 655360;                   // 128
    int* boff   = bsum + 128;                     // 128
    bf16_t* W1h  = (bf16_t*)(boff + 128);         // 65536 bf16 each (frag order)
    bf16_t* W1lo = W1h + 65536;
    bf16_t* W2h  = W1lo + 65536;
    bf16_t* W2lo = W2h + 65536;
    float* aggA = (float*)(W2lo + 65536);         // 12.8M f32 (layer-1 agg)
    float* C2   = aggA + 12800000;                // GBLK*64*256 f32
    float* h2   = C2 + (size_t)GBLK * 64 * 256;   // 12.8M f32
    float* q3   = h2 + 12800000;                  // 200000

    // ---- CSR build (multi-block scan) ----
    hipMemsetAsync(deg, 0, NN * sizeof(int), stream);
    k_hist<<<(NE + 255) / 256, 256, 0, stream>>>(dst, deg);
    k_bsum<<<NBLK, 1024, 0, stream>>>(deg, bsum);
    k_bscan<<<1, 64, 0, stream>>>(bsum, boff, rowptr);
    k_scan2<<<NBLK, 1024, 0, stream>>>(deg, boff, rowptr, cursor);
    k_fill<<<(NE + 255) / 256, 256, 0, stream>>>(src, dst, cursor, csr);

    // ---- weight split (fragment order, both layers in one kernel) ----
    k_split_w<<<512, 256, 0, stream>>>(W1l, W1r, W2l, W2r, W1h, W1lo, W2h, W2lo);

    // ---- layer 1 gather ----
    k_gather128s<<<(NN * 32 + 255) / 256, 256, 0, stream>>>(x, rowptr, csr, aggA);

    // ---- fused layer-1 + layer-2 GEMM (h1 never leaves LDS) ----
    k_gemm_fused<<<GBLK, 256, 0, stream>>>(aggA, x, W1h, W1lo, W2h, W2lo, b1, C2);

    // ---- layer-2 tail (gather+combine+q3 fused) ----
    k_gather_combine<<<(NN * 32 + 255) / 256, 256, 0, stream>>>(C2, rowptr, csr, b2, W3l, h2, q3);

    // ---- layer 3 ----
    k_final<<<(NN + 255) / 256, 256, 0, stream>>>(h2, W3r, b3, q3, rowptr, csr, out);
}

// Round 13
// 397.637 us; speedup vs baseline: 1.1815x; 1.0053x over previous
//
#include <hip/hip_runtime.h>
#include <math.h>

#define NN 100000
#define NE 640000
#define NBLK 98       // ceil(NN / 1024)
#define GBLK 1563     // ceil(NN / 64)

typedef __bf16 bf16_t;
typedef bf16_t bf16x8 __attribute__((ext_vector_type(8)));
typedef float  f32x4  __attribute__((ext_vector_type(4)));

// ================= CSR build =================

__global__ __launch_bounds__(256) void k_hist(const int* __restrict__ dst,
                                              int* __restrict__ deg) {
    int e = blockIdx.x * 256 + threadIdx.x;
    if (e < NE) atomicAdd(&deg[dst[e]], 1);
}

__global__ __launch_bounds__(1024) void k_bsum(const int* __restrict__ deg,
                                               int* __restrict__ bsum) {
    __shared__ int warr[16];
    int t = threadIdx.x;
    int i = blockIdx.x * 1024 + t;
    int v = (i < NN) ? deg[i] : 0;
    int lane = t & 63, wid = t >> 6;
    #pragma unroll
    for (int off = 32; off > 0; off >>= 1) v += __shfl_xor(v, off, 64);
    if (lane == 0) warr[wid] = v;
    __syncthreads();
    if (t < 16) {
        int s = warr[t];
        #pragma unroll
        for (int off = 8; off > 0; off >>= 1) s += __shfl_xor(s, off, 64);
        if (t == 0) bsum[blockIdx.x] = s;
    }
}

__global__ __launch_bounds__(64) void k_bscan(const int* __restrict__ bsum,
        int* __restrict__ boff, int* __restrict__ rowptr) {
    int lane = threadIdx.x;
    int carry = 0;
    for (int base = 0; base < NBLK; base += 64) {
        int i = base + lane;
        int v = (i < NBLK) ? bsum[i] : 0;
        int s = v;
        #pragma unroll
        for (int off = 1; off < 64; off <<= 1) {
            int u = __shfl_up(s, off, 64);
            if (lane >= off) s += u;
        }
        if (i < NBLK) boff[i] = carry + s - v;
        carry += __shfl(s, 63, 64);
    }
    if (lane == 0) rowptr[NN] = NE;
}

__global__ __launch_bounds__(1024) void k_scan2(const int* __restrict__ deg,
        const int* __restrict__ boff, int* __restrict__ rowptr,
        int* __restrict__ cursor) {
    __shared__ int wsum[16];
    __shared__ int woff[16];
    int t = threadIdx.x;
    int lane = t & 63, wid = t >> 6;
    int i = blockIdx.x * 1024 + t;
    int v = (i < NN) ? deg[i] : 0;
    int s = v;
    #pragma unroll
    for (int off = 1; off < 64; off <<= 1) {
        int u = __shfl_up(s, off, 64);
        if (lane >= off) s += u;
    }
    if (lane == 63) wsum[wid] = s;
    __syncthreads();
    if (wid == 0) {
        int ws = (lane < 16) ? wsum[lane] : 0;
        #pragma unroll
        for (int off = 1; off < 16; off <<= 1) {
            int u = __shfl_up(ws, off, 64);
            if (lane >= off) ws += u;
        }
        if (lane < 16) woff[lane] = ws;
    }
    __syncthreads();
    if (i < NN) {
        int excl = boff[blockIdx.x] + (s - v) + (wid ? woff[wid - 1] : 0);
        rowptr[i] = excl;
        cursor[i] = excl;
    }
}

__global__ __launch_bounds__(256) void k_fill(const int* __restrict__ src,
        const int* __restrict__ dst, int* __restrict__ cursor,
        int* __restrict__ csr) {
    int e = blockIdx.x * 256 + threadIdx.x;
    if (e >= NE) return;
    int p = atomicAdd(&cursor[dst[e]], 1);
    csr[p] = src[e];
}

// ========== weight split (f32 -> hi/lo bf16) in MFMA B-fragment order ==========
// Wf[((ct*8 + it)*64 + lane)*8 + j] = W[col = ct*16 + (lane&15)]
//                                      [k   = it*32 + (lane>>4)*8 + j]

__global__ __launch_bounds__(256) void k_split_w(const float* __restrict__ W1l,
        const float* __restrict__ W1r, const float* __restrict__ W2l,
        const float* __restrict__ W2r, bf16_t* __restrict__ W1fh,
        bf16_t* __restrict__ W1fl, bf16_t* __restrict__ W2fh,
        bf16_t* __restrict__ W2fl) {
    int b = blockIdx.x, t = threadIdx.x;
    float f;
    bf16_t* Wfh;
    bf16_t* Wfl;
    int j;
    if (b < 256) {        // W1cat[j] = [W1l[j,:] | W1r[j,:]]
        j = b;
        f = (t < 128) ? W1l[j * 128 + t] : W1r[j * 128 + (t - 128)];
        Wfh = W1fh; Wfl = W1fl;
    } else {              // W2cat rows 0..127 = W2l, 128..255 = W2r
        j = b - 256;
        f = (j < 128) ? W2l[j * 256 + t] : W2r[(j - 128) * 256 + t];
        Wfh = W2fh; Wfl = W2fl;
    }
    bf16_t h = (bf16_t)f;
    bf16_t l = (bf16_t)(f - (float)h);
    int idx = (((j >> 4) * 8 + (t >> 5)) * 64 + ((t >> 3) & 3) * 16 + (j & 15)) * 8 + (t & 7);
    Wfh[idx] = h;
    Wfl[idx] = l;
}

// ================= gather-mean for layer 1 (f32, 128 wide) =================

__global__ __launch_bounds__(256) void k_gather128s(const float* __restrict__ feat,
        const int* __restrict__ rowptr, const int* __restrict__ csr,
        float* __restrict__ agg) {
    int tid = blockIdx.x * 256 + threadIdx.x;
    int node = tid >> 5;
    if (node >= NN) return;
    int lane4 = (tid & 31) << 2;
    int beg = rowptr[node], end = rowptr[node + 1];
    float4 acc = make_float4(0.f, 0.f, 0.f, 0.f);
    int e = beg;
    for (; e + 1 < end; e += 2) {
        int s0 = csr[e], s1 = csr[e + 1];
        float4 v0 = *(const float4*)(feat + (size_t)s0 * 128 + lane4);
        float4 v1 = *(const float4*)(feat + (size_t)s1 * 128 + lane4);
        acc.x += v0.x + v1.x; acc.y += v0.y + v1.y;
        acc.z += v0.z + v1.z; acc.w += v0.w + v1.w;
    }
    if (e < end) {
        int s0 = csr[e];
        float4 v0 = *(const float4*)(feat + (size_t)s0 * 128 + lane4);
        acc.x += v0.x; acc.y += v0.y; acc.z += v0.z; acc.w += v0.w;
    }
    float iv = 1.0f / (float)max(end - beg, 1);
    acc.x *= iv; acc.y *= iv; acc.z *= iv; acc.w *= iv;
    *(float4*)(agg + (size_t)node * 128 + lane4) = acc;
}

// ============ FUSED layer-1 + layer-2 GEMM, barrier-free K-loops =============
// Prologue: A = [agg|x] (64 rows x 256 k) split hi/lo into LDS in MFMA
// A-FRAGMENT ORDER (one pass, no barriers between steps, writes 1KB-contiguous
// per wave instruction -> conflict-free). Then:
//   Phase 1: h1 = relu(l2norm(A @ W1cat^T + b1)) — A-frags from LDS,
//            W1-frags from global frag-order. ZERO barriers, ZERO staging.
//   (barrier; overwrite LDS with h1 frags; barrier)
//   Phase 2: C2 = h1 @ W2cat^T — identical shape. ZERO barriers.
// Kernel total: 3 barriers (R12 had 17 -> the phase-1 2-barrier staging chain
// was the measured stall: MfmaUtil 29.7%, 5.6M LDS conflict-cycles).
// Frag-order index for element [r][c]: (((r>>4)*8+(c>>5))*64+((c>>3)&3)*16+(r&15))*8+(c&7)
// Reader lane reads &s[((mt*8+it)*64+lane)*8] -> 16 contiguous B/lane, 1KB/wave.

__device__ __forceinline__ void splitv(float4 v0, float4 v1,
                                       bf16x8& h, bf16x8& l) {
    float f[8] = {v0.x, v0.y, v0.z, v0.w, v1.x, v1.y, v1.z, v1.w};
    #pragma unroll
    for (int i = 0; i < 8; i++) {
        bf16_t hi = (bf16_t)f[i];
        h[i] = hi;
        l[i] = (bf16_t)(f[i] - (float)hi);
    }
}

__global__ __launch_bounds__(256, 2) void k_gemm_fused(const float* __restrict__ Aa,
        const float* __restrict__ Ax, const bf16_t* __restrict__ W1fh,
        const bf16_t* __restrict__ W1fl, const bf16_t* __restrict__ W2fh,
        const bf16_t* __restrict__ W2fl, const float* __restrict__ bias,
        float* __restrict__ C2) {
    __shared__ bf16_t sHf[64 * 256], sLf[64 * 256];  // A frags, then h1 frags
    __shared__ float pr[64][4];
    int t = threadIdx.x;
    int wave = t >> 6, lane = t & 63, quad = lane >> 4, l16 = lane & 15;
    int r0 = blockIdx.x * 64;
    int arow = t >> 2, aseg = t & 3;                 // staging: 8 f32 per thread/step
    int grow = r0 + arow; if (grow >= NN) grow = NN - 1;
    // ---------- prologue: stage ALL of A (K=256) in frag order, hi/lo ----------
    // writer idx: r=arow fixed, c = it*32 + aseg*8 + j ->
    //   idx = (((arow>>4)*8 + it)*64 + aseg*16 + (arow&15))*8 + j  (j=0..7 contig)
    #pragma unroll
    for (int it = 0; it < 8; it++) {
        int k0 = it * 32;
        const float* Asrc = (k0 < 128) ? Aa : Ax;
        int kb = (k0 < 128) ? k0 : (k0 - 128);
        const float* p = &Asrc[(size_t)grow * 128 + kb + aseg * 8];
        bf16x8 h8, l8;
        splitv(*(const float4*)p, *(const float4*)(p + 4), h8, l8);
        int idx = (((arow >> 4) * 8 + it) * 64 + aseg * 16 + (arow & 15)) * 8;
        *(bf16x8*)&sHf[idx] = h8;
        *(bf16x8*)&sLf[idx] = l8;
    }
    __syncthreads();
    // ---------- phase 1 K-loop: no barriers, no staging ----------
    f32x4 acc[4][4] = {};
    for (int it = 0; it < 8; it++) {
        bf16x8 bh[4], bl[4];
        #pragma unroll
        for (int nt = 0; nt < 4; nt++) {
            size_t fo = (size_t)(((wave * 4 + nt) * 8 + it) * 64 + lane) * 8;
            bh[nt] = *(const bf16x8*)&W1fh[fo];
            bl[nt] = *(const bf16x8*)&W1fl[fo];
        }
        #pragma unroll
        for (int mt = 0; mt < 4; mt++) {
            int fb = ((mt * 8 + it) * 64 + lane) * 8;
            bf16x8 ah = *(bf16x8*)&sHf[fb];
            bf16x8 al = *(bf16x8*)&sLf[fb];
            #pragma unroll
            for (int nt = 0; nt < 4; nt++) {
                acc[mt][nt] = __builtin_amdgcn_mfma_f32_16x16x32_bf16(ah, bh[nt], acc[mt][nt], 0, 0, 0);
                acc[mt][nt] = __builtin_amdgcn_mfma_f32_16x16x32_bf16(al, bh[nt], acc[mt][nt], 0, 0, 0);
                acc[mt][nt] = __builtin_amdgcn_mfma_f32_16x16x32_bf16(ah, bl[nt], acc[mt][nt], 0, 0, 0);
            }
        }
    }
    // ---------- epilogue 1: bias + row L2-norm + relu ----------
    float bcol[4];
    #pragma unroll
    for (int nt = 0; nt < 4; nt++) bcol[nt] = bias[wave * 64 + nt * 16 + l16];
    #pragma unroll
    for (int mt = 0; mt < 4; mt++)
        #pragma unroll
        for (int nt = 0; nt < 4; nt++)
            #pragma unroll
            for (int rg = 0; rg < 4; rg++)
                acc[mt][nt][rg] += bcol[nt];
    float ss[4][4];
    #pragma unroll
    for (int mt = 0; mt < 4; mt++)
        #pragma unroll
        for (int rg = 0; rg < 4; rg++) {
            float s = 0.f;
            #pragma unroll
            for (int nt = 0; nt < 4; nt++) s += acc[mt][nt][rg] * acc[mt][nt][rg];
            #pragma unroll
            for (int off = 1; off < 16; off <<= 1) s += __shfl_xor(s, off, 64);
            ss[mt][rg] = s;
        }
    if (l16 == 0) {
        #pragma unroll
        for (int mt = 0; mt < 4; mt++)
            #pragma unroll
            for (int rg = 0; rg < 4; rg++)
                pr[mt * 16 + quad * 4 + rg][wave] = ss[mt][rg];
    }
    __syncthreads();   // all phase-1 LDS reads done; pr visible
    // ---------- h1 tile -> LDS (fragment order, hi/lo), overwriting A ----------
    #pragma unroll
    for (int mt = 0; mt < 4; mt++)
        #pragma unroll
        for (int rg = 0; rg < 4; rg++) {
            int r = mt * 16 + quad * 4 + rg;
            float tot = pr[r][0] + pr[r][1] + pr[r][2] + pr[r][3];
            float inv = 1.0f / fmaxf(sqrtf(tot), 1e-12f);
            #pragma unroll
            for (int nt = 0; nt < 4; nt++) {
                int c = wave * 64 + nt * 16 + l16;
                float v = fmaxf(acc[mt][nt][rg] * inv, 0.f);
                bf16_t h = (bf16_t)v;
                bf16_t l = (bf16_t)(v - (float)h);
                int idx = (((r >> 4) * 8 + (c >> 5)) * 64 + ((c >> 3) & 3) * 16 + (r & 15)) * 8 + (c & 7);
                sHf[idx] = h;
                sLf[idx] = l;
            }
        }
    __syncthreads();
    // ---------- phase 2 K-loop: no barriers, no staging ----------
    f32x4 acc2[4][4] = {};
    for (int it = 0; it < 8; it++) {
        bf16x8 bh[4], bl[4];
        #pragma unroll
        for (int nt = 0; nt < 4; nt++) {
            size_t fo = (size_t)(((wave * 4 + nt) * 8 + it) * 64 + lane) * 8;
            bh[nt] = *(const bf16x8*)&W2fh[fo];
            bl[nt] = *(const bf16x8*)&W2fl[fo];
        }
        #pragma unroll
        for (int mt = 0; mt < 4; mt++) {
            int fb = ((mt * 8 + it) * 64 + lane) * 8;
            bf16x8 ah = *(bf16x8*)&sHf[fb];
            bf16x8 al = *(bf16x8*)&sLf[fb];
            #pragma unroll
            for (int nt = 0; nt < 4; nt++) {
                acc2[mt][nt] = __builtin_amdgcn_mfma_f32_16x16x32_bf16(ah, bh[nt], acc2[mt][nt], 0, 0, 0);
                acc2[mt][nt] = __builtin_amdgcn_mfma_f32_16x16x32_bf16(al, bh[nt], acc2[mt][nt], 0, 0, 0);
                acc2[mt][nt] = __builtin_amdgcn_mfma_f32_16x16x32_bf16(ah, bl[nt], acc2[mt][nt], 0, 0, 0);
            }
        }
    }
    #pragma unroll
    for (int mt = 0; mt < 4; mt++)
        #pragma unroll
        for (int rg = 0; rg < 4; rg++) {
            int row = r0 + mt * 16 + quad * 4 + rg;
            if (row >= NN) continue;
            #pragma unroll
            for (int nt = 0; nt < 4; nt++) {
                int col = wave * 64 + nt * 16 + l16;
                C2[(size_t)row * 256 + col] = acc2[mt][nt][rg];
            }
        }
}

// ==== fused layer-2 tail: gather-mean p2 + combine + norm + q3 ====

__global__ __launch_bounds__(256) void k_gather_combine(const float* __restrict__ C2,
        const int* __restrict__ rowptr, const int* __restrict__ csr,
        const float* __restrict__ b2, const float* __restrict__ W3l,
        float* __restrict__ h2, float* __restrict__ q3) {
    __shared__ float sw[256];
    int t = threadIdx.x;
    sw[t] = W3l[t];
    __syncthreads();
    int tid = blockIdx.x * 256 + t;
    int node = tid >> 5;
    if (node >= NN) return;
    int l = tid & 31;
    int lane4 = l << 2;
    int beg = rowptr[node], end = rowptr[node + 1];
    float4 acc = make_float4(0.f, 0.f, 0.f, 0.f);
    int e = beg;
    for (; e + 1 < end; e += 2) {
        int s0 = csr[e], s1 = csr[e + 1];
        float4 v0 = *(const float4*)(C2 + (size_t)s0 * 256 + lane4);
        float4 v1 = *(const float4*)(C2 + (size_t)s1 * 256 + lane4);
        acc.x += v0.x + v1.x; acc.y += v0.y + v1.y;
        acc.z += v0.z + v1.z; acc.w += v0.w + v1.w;
    }
    if (e < end) {
        int s0 = csr[e];
        float4 v0 = *(const float4*)(C2 + (size_t)s0 * 256 + lane4);
        acc.x += v0.x; acc.y += v0.y; acc.z += v0.z; acc.w += v0.w;
    }
    float iv = 1.0f / (float)max(end - beg, 1);
    float4 r = *(const float4*)&C2[(size_t)node * 256 + 128 + lane4];
    float4 b = *(const float4*)&b2[lane4];
    float v0 = acc.x * iv + r.x + b.x;
    float v1 = acc.y * iv + r.y + b.y;
    float v2 = acc.z * iv + r.z + b.z;
    float v3 = acc.w * iv + r.w + b.w;
    float s = v0 * v0 + v1 * v1 + v2 * v2 + v3 * v3;
    #pragma unroll
    for (int off = 16; off > 0; off >>= 1) s += __shfl_xor(s, off, 64);
    float invn = 1.0f / fmaxf(sqrtf(s), 1e-12f);
    float4 o;
    o.x = fmaxf(v0 * invn, 0.f); o.y = fmaxf(v1 * invn, 0.f);
    o.z = fmaxf(v2 * invn, 0.f); o.w = fmaxf(v3 * invn, 0.f);
    *(float4*)&h2[(size_t)node * 128 + lane4] = o;
    float a0 = o.x * sw[lane4] + o.y * sw[lane4+1] + o.z * sw[lane4+2] + o.w * sw[lane4+3];
    float a1 = o.x * sw[128+lane4] + o.y * sw[129+lane4] + o.z * sw[130+lane4] + o.w * sw[131+lane4];
    #pragma unroll
    for (int off = 16; off > 0; off >>= 1) {
        a0 += __shfl_xor(a0, off, 64);
        a1 += __shfl_xor(a1, off, 64);
    }
    if (l == 0) {
        q3[2 * node] = a0;
        q3[2 * node + 1] = a1;
    }
}

// ================= final (absorbs the 2-wide q3 gather) =================

__global__ __launch_bounds__(256) void k_final(const float* __restrict__ h2,
        const float* __restrict__ W3r, const float* __restrict__ b3,
        const float* __restrict__ q3, const int* __restrict__ rowptr,
        const int* __restrict__ csr, float* __restrict__ out) {
    __shared__ float sw[256];
    int t = threadIdx.x;
    sw[t] = W3r[t];
    __syncthreads();
    int i = blockIdx.x * 256 + t;
    if (i >= NN) return;
    int beg = rowptr[i], end = rowptr[i + 1];
    float g0 = 0.f, g1 = 0.f;
    for (int e = beg; e < end; e++) {
        int s = csr[e];
        g0 += q3[2 * s];
        g1 += q3[2 * s + 1];
    }
    float ivd = 1.0f / (float)max(end - beg, 1);
    g0 *= ivd; g1 *= ivd;
    const float4* row = (const float4*)(h2 + (size_t)i * 128);
    float a0 = 0.f, a1 = 0.f;
    #pragma unroll
    for (int q = 0; q < 32; q++) {
        float4 v = row[q];
        a0 += v.x * sw[4*q] + v.y * sw[4*q+1] + v.z * sw[4*q+2] + v.w * sw[4*q+3];
        a1 += v.x * sw[128+4*q] + v.y * sw[129+4*q] + v.z * sw[130+4*q] + v.w * sw[131+4*q];
    }
    float v0 = g0 + a0 + b3[0];
    float v1 = g1 + a1 + b3[1];
    float invn = 1.0f / fmaxf(sqrtf(v0 * v0 + v1 * v1), 1e-12f);
    v0 *= invn; v1 *= invn;
    float mx = fmaxf(v0, v1);
    float l = logf(expf(v0 - mx) + expf(v1 - mx));
    out[2 * i] = v0 - mx - l;
    out[2 * i + 1] = v1 - mx - l;
}

// ================= launch =================

extern "C" void kernel_launch(void* const* d_in, const int* in_sizes, int n_in,
                              void* d_out, int out_size, void* d_ws, size_t ws_size,
                              hipStream_t stream) {
    const float* x   = (const float*)d_in[0];
    const int*   ei  = (const int*)d_in[1];
    const float* W1l = (const float*)d_in[2];
    const float* W1r = (const float*)d_in[3];
    const float* b1  = (const float*)d_in[4];
    const float* W2l = (const float*)d_in[5];
    const float* W2r = (const float*)d_in[6];
    const float* b2  = (const float*)d_in[7];
    const float* W3l = (const float*)d_in[8];
    const float* W3r = (const float*)d_in[9];
    const float* b3  = (const float*)d_in[10];
    float* out = (float*)d_out;
    const int* src = ei;
    const int* dst = ei + NE;

    // ---- workspace layout ----
    int* deg    = (int*)d_ws;                     // 102400
    int* rowptr = deg + 102400;
    int* cursor = rowptr + 102400;
    int* csr    = cursor + 102400;                // 655360
    int* bsum   = csr + 655360;                   // 128
    int* boff   = bsum + 128;                     // 128
    bf16_t* W1h  = (bf16_t*)(boff + 128);         // 65536 bf16 each (frag order)
    bf16_t* W1lo = W1h + 65536;
    bf16_t* W2h  = W1lo + 65536;
    bf16_t* W2lo = W2h + 65536;
    float* aggA = (float*)(W2lo + 65536);         // 12.8M f32 (layer-1 agg)
    float* C2   = aggA + 12800000;                // GBLK*64*256 f32
    float* h2   = C2 + (size_t)GBLK * 64 * 256;   // 12.8M f32
    float* q3   = h2 + 12800000;                  // 200000

    // ---- CSR build (multi-block scan) ----
    hipMemsetAsync(deg, 0, NN * sizeof(int), stream);
    k_hist<<<(NE + 255) / 256, 256, 0, stream>>>(dst, deg);
    k_bsum<<<NBLK, 1024, 0, stream>>>(deg, bsum);
    k_bscan<<<1, 64, 0, stream>>>(bsum, boff, rowptr);
    k_scan2<<<NBLK, 1024, 0, stream>>>(deg, boff, rowptr, cursor);
    k_fill<<<(NE + 255) / 256, 256, 0, stream>>>(src, dst, cursor, csr);

    // ---- weight split (fragment order, both layers in one kernel) ----
    k_split_w<<<512, 256, 0, stream>>>(W1l, W1r, W2l, W2r, W1h, W1lo, W2h, W2lo);

    // ---- layer 1 gather ----
    k_gather128s<<<(NN * 32 + 255) / 256, 256, 0, stream>>>(x, rowptr, csr, aggA);

    // ---- fused layer-1 + layer-2 GEMM (h1 never leaves LDS) ----
    k_gemm_fused<<<GBLK, 256, 0, stream>>>(aggA, x, W1h, W1lo, W2h, W2lo, b1, C2);

    // ---- layer-2 tail (gather+combine+q3 fused) ----
    k_gather_combine<<<(NN * 32 + 255) / 256, 256, 0, stream>>>(C2, rowptr, csr, b2, W3l, h2, q3);

    // ---- layer 3 ----
    k_final<<<(NN + 255) / 256, 256, 0, stream>>>(h2, W3r, b3, q3, rowptr, csr, out);
}